// Round 5
// baseline (248.076 us; speedup 1.0000x reference)
//
#include <hip/hip_runtime.h>
#include <hip/hip_bf16.h>
#include <stdint.h>

typedef __attribute__((ext_vector_type(8))) short short8;
typedef __bf16 bf16x8 __attribute__((ext_vector_type(8)));
typedef __attribute__((ext_vector_type(4))) float f32x4;

#define HID 128
#define NTILES 8   // 8 hid tiles of 16 -> 128 hidden units
#define KSTEPS 4   // 4 K-steps of 32 -> K=128

// ws layout (float index): [0,8192) afrag (short[16384], W as A-operand frags);
// [8192,8320) c; [8320,8448) w2; [8448] b2.  LDS copy: 2112*int4 = 33792 B.
#define WS_C_F    8192
#define WS_W2_F   8320
#define WS_B2_F   8448

#define GRID_BLOCKS 1024
#define TOTAL_WAVES (GRID_BLOCKS * 8)

// ---------------- prep (grid=20): b0-2 heads, b3 c/w2/b2, b4-19 pack W frags
__global__ void prep_kernel(const float* __restrict__ node_hidden,
                            const float* __restrict__ h_glob,
                            const float* __restrict__ state,
                            const float* __restrict__ validity,
                            const float* __restrict__ W_hl1, const float* __restrict__ b_hl1,
                            const float* __restrict__ W_hl2, const float* __restrict__ b_hl2,
                            const float* __restrict__ W_in1, const float* __restrict__ b_in1,
                            const float* __restrict__ W_in2, const float* __restrict__ b_in2,
                            const float* __restrict__ W_ex1, const float* __restrict__ b_ex1,
                            const float* __restrict__ W_ex2, const float* __restrict__ b_ex2,
                            const float* __restrict__ W_tp1, const float* __restrict__ b_tp1,
                            const float* __restrict__ W_tp2, const float* __restrict__ b_tp2,
                            float* __restrict__ out, float* __restrict__ ws)
{
    const int tid = threadIdx.x;
    const int b = blockIdx.x;

    if (b < 3) {
        __shared__ float feats[264];
        __shared__ float hidden[128];
        const float* W1 = (b == 0) ? W_hl1 : (b == 1 ? W_in1 : W_ex1);
        const float* b1 = (b == 0) ? b_hl1 : (b == 1 ? b_in1 : b_ex1);
        const float* W2 = (b == 0) ? W_hl2 : (b == 1 ? W_in2 : W_ex2);
        const float* b2 = (b == 0) ? b_hl2 : (b == 1 ? b_in2 : b_ex2);
        const int od    = (b == 0) ? 4 : (b == 1 ? 5 : 30);
        const int obase = (b == 0) ? 0 : (b == 1 ? 4 : 9);

        for (int i = tid; i < 264; i += 256) {
            float v;
            if (i < 128)      v = node_hidden[i];   // feats = [cur, h_glob, state]
            else if (i < 256) v = h_glob[i - 128];
            else              v = state[i - 256];
            feats[i] = v;
        }
        __syncthreads();
        if (tid < 128) {
            float h = b1[tid];
            for (int i = 0; i < 264; ++i) h += feats[i] * W1[i * 128 + tid];
            hidden[tid] = fmaxf(h, 0.f);
        }
        __syncthreads();
        if (tid < od) {
            float o = b2[tid];
            for (int i = 0; i < 128; ++i) o += hidden[i] * W2[i * od + tid];
            if (b == 2) o += logf(validity[tid]);
            out[obase + tid] = o;
        }
    } else if (b == 3) {
        // c = b_tp1 + h_glob @ W_tp1[0:128] + state @ W_tp1[256:264]; also w2, b2
        if (tid < 128) {
            float c = b_tp1[tid];
            for (int i = 0; i < 128; ++i) c += h_glob[i] * W_tp1[i * HID + tid];
            for (int i = 0; i < 8;  ++i)  c += state[i] * W_tp1[(256 + i) * HID + tid];
            ws[WS_C_F  + tid] = c;
            ws[WS_W2_F + tid] = W_tp2[tid];
            if (tid == 0) ws[WS_B2_F] = b_tp2[0];
        }
    } else {
        // pack A-operand frags of W = W_tp1[128:256,:]: A[row=hid][k] = W_tp1[128+k][hid]
        // frag: row = lane&15, k = (lane>>4)*8 + j  (16B per lane per (t,s))
        short* afrag = (short*)ws;
        const int part = b - 4;                       // 0..15, 1024 entries each
        for (int idx = part * 1024 + tid; idx < part * 1024 + 1024; idx += 256) {
            const int k = idx >> 7, nn = idx & 127;   // source (k, hid)
            const int t = nn >> 4, cc = nn & 15;
            const int s = k >> 5, rr = k & 31;
            const int g = rr >> 3, j = rr & 7;
            const int lane = cc + (g << 4);
            afrag[(((t * KSTEPS + s) * 64 + lane) << 3) + j] =
                (short)__builtin_bit_cast(unsigned short, (__bf16)W_tp1[(128 + k) * HID + nn]);
        }
    }
}

// ---------------- teleport: 32 nodes (a chunk-pair) per wave-iteration.
// W is the A-operand (shared ds_read feeds both chunks); nodes are B-operand.
// C[row=hid_local, col=node] -> per-lane scalar partials, 2-shfl reduce,
// 32-lane contiguous dword store.
__launch_bounds__(512, 6)
__global__ void teleport_kernel(const float* __restrict__ node_hidden, // n x 128
                                const float* __restrict__ ws,          // packed weights
                                float* __restrict__ out,               // pre-offset (+39)
                                int n)
{
    __shared__ __align__(16) unsigned char smem[33792]; // afrag 32KB | c 512B | w2 512B
    const int tid = threadIdx.x;

    {
        const int4* wsv = (const int4*)ws;
        int4* sv = (int4*)smem;
        for (int i = tid; i < 2112; i += 512) sv[i] = wsv[i];
    }
    const float bias2 = ws[WS_B2_F];
    __syncthreads();

    const short* afrag = (const short*)smem;
    const float* c_all  = (const float*)(smem + 32768);
    const float* w2_all = (const float*)(smem + 33280);

    const int lane = tid & 63;
    const int wave = tid >> 6;
    const int m = lane & 15;   // B col: node index within 16-row chunk
    const int g = lane >> 4;   // k-group; also C row-group (hid_local = g*4+r)

    const int nPairs = (n + 31) >> 5;
    const int gw = blockIdx.x * 8 + wave;
    const int p0 = (int)(((long long)gw * nPairs) / TOTAL_WAVES);
    const int p1 = (int)(((long long)(gw + 1) * nPairs) / TOTAL_WAVES);

    for (int p = p0; p < p1; ++p) {
        const int rowA = min(p * 32 + m,      n - 1);
        const int rowB = min(p * 32 + 16 + m, n - 1);
        const float4* ArA = (const float4*)(node_hidden + (size_t)rowA * HID);
        const float4* ArB = (const float4*)(node_hidden + (size_t)rowB * HID);

        bf16x8 ndA[KSTEPS], ndB[KSTEPS];
        #pragma unroll
        for (int s = 0; s < KSTEPS; ++s) {
            const float4 fa = ArA[s * 8 + g * 2];
            const float4 fb = ArA[s * 8 + g * 2 + 1];
            bf16x8 a;
            a[0] = (__bf16)fa.x; a[1] = (__bf16)fa.y; a[2] = (__bf16)fa.z; a[3] = (__bf16)fa.w;
            a[4] = (__bf16)fb.x; a[5] = (__bf16)fb.y; a[6] = (__bf16)fb.z; a[7] = (__bf16)fb.w;
            ndA[s] = a;
        }
        #pragma unroll
        for (int s = 0; s < KSTEPS; ++s) {
            const float4 fa = ArB[s * 8 + g * 2];
            const float4 fb = ArB[s * 8 + g * 2 + 1];
            bf16x8 a;
            a[0] = (__bf16)fa.x; a[1] = (__bf16)fa.y; a[2] = (__bf16)fa.z; a[3] = (__bf16)fa.w;
            a[4] = (__bf16)fb.x; a[5] = (__bf16)fb.y; a[6] = (__bf16)fb.z; a[7] = (__bf16)fb.w;
            ndB[s] = a;
        }

        float srA = 0.f, srB = 0.f;
        #pragma unroll
        for (int t = 0; t < NTILES; ++t) {
            f32x4 a0 = (f32x4){0.f, 0.f, 0.f, 0.f};
            f32x4 a1 = (f32x4){0.f, 0.f, 0.f, 0.f};
            #pragma unroll
            for (int s = 0; s < KSTEPS; ++s) {
                const short8 wsv = *(const short8*)&afrag[(((t * KSTEPS + s) * 64 + lane) << 3)];
                const bf16x8 wf = __builtin_bit_cast(bf16x8, wsv);
                a0 = __builtin_amdgcn_mfma_f32_16x16x32_bf16(wf, ndA[s], a0, 0, 0, 0);
                a1 = __builtin_amdgcn_mfma_f32_16x16x32_bf16(wf, ndB[s], a1, 0, 0, 0);
            }
            // lane's 4 hid units: hid = t*16 + g*4 + r
            const float4 c4  = *(const float4*)(c_all  + t * 16 + g * 4);
            const float4 w4  = *(const float4*)(w2_all + t * 16 + g * 4);
            const float cc[4] = {c4.x, c4.y, c4.z, c4.w};
            const float ww[4] = {w4.x, w4.y, w4.z, w4.w};
            #pragma unroll
            for (int r = 0; r < 4; ++r) {
                float hA = a0[r] + cc[r]; hA = hA > 0.f ? hA : 0.f; srA += hA * ww[r];
                float hB = a1[r] + cc[r]; hB = hB > 0.f ? hB : 0.f; srB += hB * ww[r];
            }
        }

        // sum the 4 g-groups (lanes differing in bits 4,5)
        srA += __shfl_xor(srA, 16, 64); srA += __shfl_xor(srA, 32, 64);
        srB += __shfl_xor(srB, 16, 64); srB += __shfl_xor(srB, 32, 64);

        // lanes 0..31 store one contiguous 128B segment of 32 results
        if (lane < 32) {
            const int o = p * 32 + lane;
            const float v = (lane < 16 ? srA : srB) + bias2;
            if (o < n) out[o] = v;
        }
    }
}

extern "C" void kernel_launch(void* const* d_in, const int* in_sizes, int n_in,
                              void* d_out, int out_size, void* d_ws, size_t ws_size,
                              hipStream_t stream) {
    const float* node_hidden = (const float*)d_in[0];
    const float* h_glob      = (const float*)d_in[1];
    const float* state       = (const float*)d_in[2];
    const float* validity    = (const float*)d_in[3];
    const float* W_hl1 = (const float*)d_in[4];  const float* b_hl1 = (const float*)d_in[5];
    const float* W_hl2 = (const float*)d_in[6];  const float* b_hl2 = (const float*)d_in[7];
    const float* W_in1 = (const float*)d_in[8];  const float* b_in1 = (const float*)d_in[9];
    const float* W_in2 = (const float*)d_in[10]; const float* b_in2 = (const float*)d_in[11];
    const float* W_ex1 = (const float*)d_in[12]; const float* b_ex1 = (const float*)d_in[13];
    const float* W_ex2 = (const float*)d_in[14]; const float* b_ex2 = (const float*)d_in[15];
    const float* W_tp1 = (const float*)d_in[16]; const float* b_tp1 = (const float*)d_in[17];
    const float* W_tp2 = (const float*)d_in[18]; const float* b_tp2 = (const float*)d_in[19];

    float* out = (float*)d_out;
    float* ws  = (float*)d_ws;
    const int n = in_sizes[0] / HID;   // 400000

    prep_kernel<<<20, 256, 0, stream>>>(node_hidden, h_glob, state, validity,
                                        W_hl1, b_hl1, W_hl2, b_hl2,
                                        W_in1, b_in1, W_in2, b_in2,
                                        W_ex1, b_ex1, W_ex2, b_ex2,
                                        W_tp1, b_tp1, W_tp2, b_tp2,
                                        out, ws);
    teleport_kernel<<<GRID_BLOCKS, 512, 0, stream>>>(node_hidden, ws, out + 39, n);
}

// Round 6
// 61.131 us; speedup vs baseline: 4.0581x; 4.0581x over previous
//
#include <hip/hip_runtime.h>
#include <hip/hip_bf16.h>
#include <stdint.h>

typedef __attribute__((ext_vector_type(8))) short short8;
typedef __bf16 bf16x8 __attribute__((ext_vector_type(8)));
typedef __attribute__((ext_vector_type(4))) float f32x4;

#define HID 128
#define NTILES 8   // 8 hid tiles of 16 -> 128 hidden units
#define KSTEPS 4   // 4 K-steps of 32 -> K=128

// ws layout (float index): [0,8192) afrag (short[16384], W as A-operand frags);
// [8192,8320) c; [8320,8448) w2; [8448] b2.  LDS copy: 2112*int4 = 33792 B.
#define WS_C_F    8192
#define WS_W2_F   8320
#define WS_B2_F   8448

#define GRID_BLOCKS 1024
#define WAVES_PER_BLOCK 8

// ---------------- prep (grid=20): b0-2 heads, b3 c/w2/b2, b4-19 pack W frags
__global__ void prep_kernel(const float* __restrict__ node_hidden,
                            const float* __restrict__ h_glob,
                            const float* __restrict__ state,
                            const float* __restrict__ validity,
                            const float* __restrict__ W_hl1, const float* __restrict__ b_hl1,
                            const float* __restrict__ W_hl2, const float* __restrict__ b_hl2,
                            const float* __restrict__ W_in1, const float* __restrict__ b_in1,
                            const float* __restrict__ W_in2, const float* __restrict__ b_in2,
                            const float* __restrict__ W_ex1, const float* __restrict__ b_ex1,
                            const float* __restrict__ W_ex2, const float* __restrict__ b_ex2,
                            const float* __restrict__ W_tp1, const float* __restrict__ b_tp1,
                            const float* __restrict__ W_tp2, const float* __restrict__ b_tp2,
                            float* __restrict__ out, float* __restrict__ ws)
{
    const int tid = threadIdx.x;
    const int b = blockIdx.x;

    if (b < 3) {
        __shared__ float feats[264];
        __shared__ float hidden[128];
        const float* W1 = (b == 0) ? W_hl1 : (b == 1 ? W_in1 : W_ex1);
        const float* b1 = (b == 0) ? b_hl1 : (b == 1 ? b_in1 : b_ex1);
        const float* W2 = (b == 0) ? W_hl2 : (b == 1 ? W_in2 : W_ex2);
        const float* b2 = (b == 0) ? b_hl2 : (b == 1 ? b_in2 : b_ex2);
        const int od    = (b == 0) ? 4 : (b == 1 ? 5 : 30);
        const int obase = (b == 0) ? 0 : (b == 1 ? 4 : 9);

        for (int i = tid; i < 264; i += 256) {
            float v;
            if (i < 128)      v = node_hidden[i];   // feats = [cur, h_glob, state]
            else if (i < 256) v = h_glob[i - 128];
            else              v = state[i - 256];
            feats[i] = v;
        }
        __syncthreads();
        if (tid < 128) {
            float h = b1[tid];
            for (int i = 0; i < 264; ++i) h += feats[i] * W1[i * 128 + tid];
            hidden[tid] = fmaxf(h, 0.f);
        }
        __syncthreads();
        if (tid < od) {
            float o = b2[tid];
            for (int i = 0; i < 128; ++i) o += hidden[i] * W2[i * od + tid];
            if (b == 2) o += logf(validity[tid]);
            out[obase + tid] = o;
        }
    } else if (b == 3) {
        // c = b_tp1 + h_glob @ W_tp1[0:128] + state @ W_tp1[256:264]; also w2, b2
        if (tid < 128) {
            float c = b_tp1[tid];
            for (int i = 0; i < 128; ++i) c += h_glob[i] * W_tp1[i * HID + tid];
            for (int i = 0; i < 8;  ++i)  c += state[i] * W_tp1[(256 + i) * HID + tid];
            ws[WS_C_F  + tid] = c;
            ws[WS_W2_F + tid] = W_tp2[tid];
            if (tid == 0) ws[WS_B2_F] = b_tp2[0];
        }
    } else {
        // pack A-operand frags of W = W_tp1[128:256,:]: A[row=hid][k] = W_tp1[128+k][hid]
        // frag: row = lane&15, k = (lane>>4)*8 + j  (16B per lane per (t,s))
        short* afrag = (short*)ws;
        const int part = b - 4;                       // 0..15, 1024 entries each
        for (int idx = part * 1024 + tid; idx < part * 1024 + 1024; idx += 256) {
            const int k = idx >> 7, nn = idx & 127;   // source (k, hid)
            const int t = nn >> 4, cc = nn & 15;
            const int s = k >> 5, rr = k & 31;
            const int g = rr >> 3, j = rr & 7;
            const int lane = cc + (g << 4);
            afrag[(((t * KSTEPS + s) * 64 + lane) << 3) + j] =
                (short)__builtin_bit_cast(unsigned short, (__bf16)W_tp1[(128 + k) * HID + nn]);
        }
    }
}

// ---------------- teleport: 16 nodes per wave-iteration, W as A-operand.
// C[row=hid_local, col=node] -> per-lane scalar partial, 2-shfl reduce,
// 16-lane contiguous dword store. Live state ~45 VGPR (no spills, high TLP).
__launch_bounds__(512)
__global__ void teleport_kernel(const float* __restrict__ node_hidden, // n x 128
                                const float* __restrict__ ws,          // packed weights
                                float* __restrict__ out,               // pre-offset (+39)
                                int n)
{
    __shared__ __align__(16) unsigned char smem[33792]; // afrag 32KB | c 512B | w2 512B
    const int tid = threadIdx.x;

    {
        const int4* wsv = (const int4*)ws;
        int4* sv = (int4*)smem;
        for (int i = tid; i < 2112; i += 512) sv[i] = wsv[i];
    }
    const float bias2 = ws[WS_B2_F];
    __syncthreads();

    const short* afrag  = (const short*)smem;
    const float* c_all  = (const float*)(smem + 32768);
    const float* w2_all = (const float*)(smem + 33280);

    const int lane = tid & 63;
    const int wave = tid >> 6;
    const int m = lane & 15;   // B col: node index within chunk
    const int g = lane >> 4;   // k-group; C row-group (hid_local = g*4+r)

    const int nChunks = (n + 15) >> 4;
    const int gstride = gridDim.x * WAVES_PER_BLOCK;

    for (int c = blockIdx.x * WAVES_PER_BLOCK + wave; c < nChunks; c += gstride) {
        const int row = min(c * 16 + m, n - 1);
        const float4* Ar = (const float4*)(node_hidden + (size_t)row * HID);

        // load + convert this chunk's node B-fragments: 4 x bf16x8 (16 VGPRs)
        bf16x8 nd[KSTEPS];
        #pragma unroll
        for (int s = 0; s < KSTEPS; ++s) {
            const float4 fa = Ar[s * 8 + g * 2];
            const float4 fb = Ar[s * 8 + g * 2 + 1];
            bf16x8 a;
            a[0] = (__bf16)fa.x; a[1] = (__bf16)fa.y; a[2] = (__bf16)fa.z; a[3] = (__bf16)fa.w;
            a[4] = (__bf16)fb.x; a[5] = (__bf16)fb.y; a[6] = (__bf16)fb.z; a[7] = (__bf16)fb.w;
            nd[s] = a;
        }

        float sr = 0.f;
        #pragma unroll
        for (int t = 0; t < NTILES; ++t) {
            f32x4 acc = (f32x4){0.f, 0.f, 0.f, 0.f};
            #pragma unroll
            for (int s = 0; s < KSTEPS; ++s) {
                const short8 wv = *(const short8*)&afrag[(((t * KSTEPS + s) * 64 + lane) << 3)];
                const bf16x8 wf = __builtin_bit_cast(bf16x8, wv);
                acc = __builtin_amdgcn_mfma_f32_16x16x32_bf16(wf, nd[s], acc, 0, 0, 0);
            }
            // lane's 4 hid units: hid = t*16 + g*4 + r  (broadcast reads, 4 distinct/wave)
            const float4 c4 = *(const float4*)(c_all  + t * 16 + g * 4);
            const float4 w4 = *(const float4*)(w2_all + t * 16 + g * 4);
            float h0 = acc[0] + c4.x, h1 = acc[1] + c4.y;
            float h2 = acc[2] + c4.z, h3 = acc[3] + c4.w;
            h0 = h0 > 0.f ? h0 : 0.f;  h1 = h1 > 0.f ? h1 : 0.f;
            h2 = h2 > 0.f ? h2 : 0.f;  h3 = h3 > 0.f ? h3 : 0.f;
            sr += h0 * w4.x + h1 * w4.y + h2 * w4.z + h3 * w4.w;
        }

        // sum across the 4 g-groups (lanes differing in bits 4,5)
        sr += __shfl_xor(sr, 16, 64);
        sr += __shfl_xor(sr, 32, 64);

        // lanes 0..15 store 16 contiguous dwords (64B per wave)
        if (lane < 16) {
            const int o = c * 16 + lane;
            if (o < n) out[o] = sr + bias2;
        }
    }
}

extern "C" void kernel_launch(void* const* d_in, const int* in_sizes, int n_in,
                              void* d_out, int out_size, void* d_ws, size_t ws_size,
                              hipStream_t stream) {
    const float* node_hidden = (const float*)d_in[0];
    const float* h_glob      = (const float*)d_in[1];
    const float* state       = (const float*)d_in[2];
    const float* validity    = (const float*)d_in[3];
    const float* W_hl1 = (const float*)d_in[4];  const float* b_hl1 = (const float*)d_in[5];
    const float* W_hl2 = (const float*)d_in[6];  const float* b_hl2 = (const float*)d_in[7];
    const float* W_in1 = (const float*)d_in[8];  const float* b_in1 = (const float*)d_in[9];
    const float* W_in2 = (const float*)d_in[10]; const float* b_in2 = (const float*)d_in[11];
    const float* W_ex1 = (const float*)d_in[12]; const float* b_ex1 = (const float*)d_in[13];
    const float* W_ex2 = (const float*)d_in[14]; const float* b_ex2 = (const float*)d_in[15];
    const float* W_tp1 = (const float*)d_in[16]; const float* b_tp1 = (const float*)d_in[17];
    const float* W_tp2 = (const float*)d_in[18]; const float* b_tp2 = (const float*)d_in[19];

    float* out = (float*)d_out;
    float* ws  = (float*)d_ws;
    const int n = in_sizes[0] / HID;   // 400000

    prep_kernel<<<20, 256, 0, stream>>>(node_hidden, h_glob, state, validity,
                                        W_hl1, b_hl1, W_hl2, b_hl2,
                                        W_in1, b_in1, W_in2, b_in2,
                                        W_ex1, b_ex1, W_ex2, b_ex2,
                                        W_tp1, b_tp1, W_tp2, b_tp2,
                                        out, ws);
    teleport_kernel<<<GRID_BLOCKS, 512, 0, stream>>>(node_hidden, ws, out + 39, n);
}